// Round 11
// baseline (224.714 us; speedup 1.0000x reference)
//
#include <hip/hip_runtime.h>
#include <stdint.h>

#define M_DIM 8192
#define N_DIM 4096
#define K_DIM 4096
#define QMAXF 127.0f
#define QDIVF 127.5f

typedef int v4i __attribute__((ext_vector_type(4)));

// ---------------- address-space helpers for global_load_lds ----------------
typedef __attribute__((address_space(3))) void lds_void_t;
typedef __attribute__((address_space(1))) const void glb_void_t;

static __device__ __forceinline__ void load_lds16(const void* g, void* l) {
    __builtin_amdgcn_global_load_lds((glb_void_t*)g, (lds_void_t*)l, 16, 0, 0);
}

// ---- kernel 1: fused prep pass 1: [row absmax+quant lhs] ∥ [col absmax rhs] ----
__global__ __launch_bounds__(256) void prep1_kernel(
        const float* __restrict__ lhs, const float* __restrict__ rhs,
        float* __restrict__ sL, unsigned* __restrict__ bits,
        int8_t* __restrict__ ql) {
    const int t = threadIdx.x;
    if (blockIdx.x < M_DIM) {
        const int row = blockIdx.x;
        const float4* rp = (const float4*)(lhs + (size_t)row * K_DIM);
        float4 v[4];
        float m = 0.0f;
#pragma unroll
        for (int i = 0; i < 4; ++i) {
            v[i] = rp[t + i * 256];
            m = fmaxf(m, fmaxf(fmaxf(fabsf(v[i].x), fabsf(v[i].y)),
                               fmaxf(fabsf(v[i].z), fabsf(v[i].w))));
        }
#pragma unroll
        for (int off = 32; off; off >>= 1) m = fmaxf(m, __shfl_down(m, off, 64));
        __shared__ float wmax[4];
        if ((t & 63) == 0) wmax[t >> 6] = m;
        __syncthreads();
        const float mm = fmaxf(fmaxf(wmax[0], wmax[1]), fmaxf(wmax[2], wmax[3]));
        float s = mm / QDIVF;
        s = (s == 0.0f) ? 1.0f : s;
        if (t == 0) sL[row] = s;
        unsigned* qo = (unsigned*)ql + (size_t)row * 1024;
#pragma unroll
        for (int i = 0; i < 4; ++i) {
            int q0 = (int)fminf(fmaxf(rintf(v[i].x / s), -QMAXF), QMAXF);
            int q1 = (int)fminf(fmaxf(rintf(v[i].y / s), -QMAXF), QMAXF);
            int q2 = (int)fminf(fmaxf(rintf(v[i].z / s), -QMAXF), QMAXF);
            int q3 = (int)fminf(fmaxf(rintf(v[i].w / s), -QMAXF), QMAXF);
            qo[t + i * 256] = (q0 & 255) | ((q1 & 255) << 8) | ((q2 & 255) << 16)
                            | ((unsigned)(q3 & 255) << 24);
        }
    } else {
        const int cb = blockIdx.x - M_DIM;     // 0..1023
        const int col = (cb & 15) * 256 + t;
        const int r0 = (cb >> 4) * 64;
        float m = 0.0f;
#pragma unroll 4
        for (int r = 0; r < 64; ++r)
            m = fmaxf(m, fabsf(rhs[(size_t)(r0 + r) * N_DIM + col]));
        atomicMax(&bits[col], __float_as_uint(m));   // abs >= 0: bit order == float order
    }
}

// -- kernel 2: quantize + transpose rhs -> q_rT [N][K]; also materialize sR --
__global__ __launch_bounds__(256) void quant_rhs_t_kernel(
        const float* __restrict__ rhs, const unsigned* __restrict__ bits,
        float* __restrict__ sR, int8_t* __restrict__ qbT) {
    __shared__ __align__(16) int8_t lt[64][80];
    const int n0 = blockIdx.x * 64;
    const int k0 = blockIdx.y * 64;
    const int t = threadIdx.x;
    const int nloc = t & 63;
    const int kq = (t >> 6) * 16;
    float s = __uint_as_float(bits[n0 + nloc]) / QDIVF;
    s = (s == 0.0f) ? 1.0f : s;
    if (blockIdx.y == 0 && t < 64) {
        float ss = __uint_as_float(bits[n0 + t]) / QDIVF;
        sR[n0 + t] = (ss == 0.0f) ? 1.0f : ss;
    }
#pragma unroll
    for (int i = 0; i < 4; ++i) {
        unsigned pack = 0;
#pragma unroll
        for (int j = 0; j < 4; ++j) {
            int kk = kq + i * 4 + j;
            float x = rhs[(size_t)(k0 + kk) * N_DIM + n0 + nloc];
            int q = (int)fminf(fmaxf(rintf(x / s), -QMAXF), QMAXF);
            pack |= (unsigned)(q & 255) << (8 * j);
        }
        *(unsigned*)&lt[nloc][kq + i * 4] = pack;
    }
    __syncthreads();
    const int nn = t >> 2, ch = t & 3;
    v4i val = *(const v4i*)&lt[nn][ch * 16];
    *(v4i*)&qbT[(size_t)(n0 + nn) * K_DIM + k0 + ch * 16] = val;
}

// == kernel 3: int8 GEMM, 256x256, BK=64, 4 waves, whole-tile reg dbuf, ring-4 ==
// The R2-R10 invariant (lgkm-wait between a tile's reads and its MFMAs) is
// removed: at tile KT a wave reads tile KT+1's 16 frags into the spare reg
// set, then runs 64 MFMAs on tile KT with NO wait; the lgkm-wait migrates to
// the next tile's MFMA batch, hiding the LDS pipe (768 cy/CU) under the MFMA
// drain (1242 cy/CU). One barrier/tile; stage(KT+3) issued after the barrier
// (ring-4 x 32KB); VMCNT(8) at tile top drains stage(KT+1) (~2 tiles slack).
// Hazards: RAW: reads of buf(KT+1) occur after VMCNT(8)+BAR that drained and
// published it. WAR: stage(KT+3) writes buf(KT-1); its last readers (tile
// KT-1 frags, read at tile KT-2) lgkm-completed before MFMA(KT-1), which
// precedes BAR(KT); stage is issued after BAR(KT). Per-wave 128x128 output
// (acc[8][8], ~400 VGPR, 1 wave/SIMD). Swizzle/staging/epilogue: validated.

#define BAR() do { asm volatile("" ::: "memory");          \
                   __builtin_amdgcn_s_barrier();           \
                   asm volatile("" ::: "memory"); } while (0)

#define VMCNT(N) asm volatile("s_waitcnt vmcnt(%0)" :: "n"(N) : "memory")

// stage all 8 halves (A 16KB + B 16KB) of tile KT into buf BQ
#define STAGE_ALL(KT, BQ) do {                                                  \
    _Pragma("unroll") for (int h = 0; h < 4; ++h)                               \
        load_lds16(gA0 + (size_t)(h * 64) * K_DIM + (size_t)(KT) * 64,          \
                   lds + (BQ) * 32768 + h * 4096 + sdst);                       \
    _Pragma("unroll") for (int h = 0; h < 4; ++h)                               \
        load_lds16(gB0 + (size_t)(h * 64) * K_DIM + (size_t)(KT) * 64,          \
                   lds + (BQ) * 32768 + 16384 + h * 4096 + sdst);               \
} while (0)

// TILE: P = KT & 1. RDN: read tile KT+1 frags into set P^1. S: stage KT+3.
// DOBAR: emit VMCNT(VM)+BAR at tile top.
#define TILE(KT, P, RDN, S, VM, DOBAR) do {                                     \
    if (DOBAR) { VMCNT(VM); BAR(); }                                            \
    if (RDN) {                                                                  \
        _Pragma("unroll") for (int mm = 0; mm < 8; ++mm)                        \
            af[(P) ^ 1][mm] = *(const v4i*)(                                    \
                lds + (((KT) + 1) & 3) * 32768 + aoff[mm]);                     \
        _Pragma("unroll") for (int nn = 0; nn < 8; ++nn)                        \
            bf[(P) ^ 1][nn] = *(const v4i*)(                                    \
                lds + (((KT) + 1) & 3) * 32768 + boff[nn]);                     \
    }                                                                           \
    if (S) STAGE_ALL((KT) + 3, ((KT) + 3) & 3);                                 \
    __builtin_amdgcn_s_setprio(1);                                              \
    _Pragma("unroll") for (int mm = 0; mm < 8; ++mm)                            \
    _Pragma("unroll") for (int nn = 0; nn < 8; ++nn)                            \
        acc[mm][nn] = __builtin_amdgcn_mfma_i32_16x16x64_i8(                    \
            af[P][mm], bf[P][nn], acc[mm][nn], 0, 0, 0);                        \
    __builtin_amdgcn_s_setprio(0);                                              \
} while (0)

__global__ __launch_bounds__(256, 1) void gemm_i8_kernel(
        const int8_t* __restrict__ qa, const int8_t* __restrict__ qbT,
        const float* __restrict__ sL, const float* __restrict__ sR,
        float* __restrict__ out) {
    __shared__ __align__(16) int8_t lds[131072];   // ring-4 x (A 16KB + B 16KB)

    const int t = threadIdx.x;
    const int wave = t >> 6;
    const int lane = t & 63;

    // 2D XCD partition (R7-validated): each XCD owns 8mt x 8nt. Bijective.
    const int bid = blockIdx.x;
    const int xcd = bid & 7;
    const int idx = bid >> 3;                    // 0..63
    const int mt = (xcd >> 1) * 8 + (idx & 7);   // 0..31
    const int nt = (xcd & 1) * 8 + (idx >> 3);   // 0..15
    const int brow = mt * 256;
    const int bcol = nt * 256;

    const int wm = (wave >> 1) * 128;    // 2x2 waves, per-wave 128x128
    const int wn = (wave & 1) * 128;

    // fragment read byte-offsets (within buf; swizzled; 64B rows)
    // A region [0,16KB): rows 0-255; B region [16KB,32KB): rows 0-255.
    int aoff[8], boff[8];
#pragma unroll
    for (int m = 0; m < 8; ++m) {
        int row = wm + m * 16 + (lane & 15);
        aoff[m] = row * 64 + (((lane >> 4) ^ ((row >> 1) & 3)) * 16);
    }
#pragma unroll
    for (int n = 0; n < 8; ++n) {
        int row = wn + n * 16 + (lane & 15);
        boff[n] = 16384 + row * 64 + (((lane >> 4) ^ ((row >> 1) & 3)) * 16);
    }

    v4i acc[8][8];
#pragma unroll
    for (int m = 0; m < 8; ++m)
#pragma unroll
        for (int n = 0; n < 8; ++n) acc[m][n] = (v4i){0, 0, 0, 0};

    // staging: 256 threads x 16B = 4KB (64 rows x 64B) per stage instr;
    // 4 instrs per operand (rows 0/64/128/192). Source chunk pre-swizzled.
    const int srow = t >> 2;                                  // 0..63
    const int lcA = (t & 3) ^ ((srow >> 1) & 3);
    const int8_t* gA0 = qa  + (size_t)(brow + srow) * K_DIM + lcA * 16;
    const int8_t* gB0 = qbT + (size_t)(bcol + srow) * K_DIM + lcA * 16;
    const int sdst = t * 16;

    v4i af[2][8], bf[2][8];

    // prologue: stage tiles 0,1,2; drain tile 0 (VMCNT(16)); publish; preload
    // f[0] <- tile0 frags. Tile 0's TILE() then does VMCNT(8) (drains tile 1)
    // + BAR before reading tile 1 frags.
    STAGE_ALL(0, 0);
    STAGE_ALL(1, 1);
    STAGE_ALL(2, 2);
    VMCNT(16);
    BAR();
#pragma unroll
    for (int mm = 0; mm < 8; ++mm)
        af[0][mm] = *(const v4i*)(lds + aoff[mm]);
#pragma unroll
    for (int nn = 0; nn < 8; ++nn)
        bf[0][nn] = *(const v4i*)(lds + boff[nn]);

    for (int kt = 0; kt < 60; kt += 4) {
        TILE(kt + 0, 0, 1, 1, 8, 1);
        TILE(kt + 1, 1, 1, 1, 8, 1);
        TILE(kt + 2, 0, 1, 1, 8, 1);
        TILE(kt + 3, 1, 1, 1, 8, 1);
    }
    TILE(60, 0, 1, 1, 8, 1);   // stages T63; reads T61
    TILE(61, 1, 1, 0, 8, 1);   // reads T62 (drains stage T62)
    TILE(62, 0, 1, 0, 0, 1);   // reads T63 (drains stage T63)
    TILE(63, 1, 0, 0, 0, 0);   // pure MFMA on f[1]

    // Epilogue (validated): 16x16 C/D: col = lane&15, row = (lane>>4)*4 + reg
    const int r4 = (lane >> 4) * 4;
    const int cc = lane & 15;
#pragma unroll
    for (int m = 0; m < 8; ++m) {
        const int grow0 = brow + wm + m * 16 + r4;
        const float s0 = sL[grow0 + 0];
        const float s1 = sL[grow0 + 1];
        const float s2 = sL[grow0 + 2];
        const float s3 = sL[grow0 + 3];
#pragma unroll
        for (int n = 0; n < 8; ++n) {
            const int gcol = bcol + wn + n * 16 + cc;
            const float sc = sR[gcol];
            float* o = out + (size_t)grow0 * N_DIM + gcol;
            o[0 * N_DIM] = (float)acc[m][n][0] * s0 * sc;
            o[1 * N_DIM] = (float)acc[m][n][1] * s1 * sc;
            o[2 * N_DIM] = (float)acc[m][n][2] * s2 * sc;
            o[3 * N_DIM] = (float)acc[m][n][3] * s3 * sc;
        }
    }
}

// ---------------- launch ----------------
extern "C" void kernel_launch(void* const* d_in, const int* in_sizes, int n_in,
                              void* d_out, int out_size, void* d_ws, size_t ws_size,
                              hipStream_t stream) {
    const float* lhs = (const float*)d_in[0];
    const float* rhs = (const float*)d_in[1];
    float* out = (float*)d_out;

    uint8_t* ws = (uint8_t*)d_ws;
    int8_t* ql    = (int8_t*)ws;                               // 33,554,432 B
    int8_t* qbT   = (int8_t*)(ws + 33554432);                  // 16,777,216 B
    float* sL     = (float*)(ws + 50331648);                   // 32,768 B
    float* sR     = (float*)(ws + 50331648 + 32768);           // 16,384 B
    unsigned* bits = (unsigned*)(ws + 50331648 + 32768 + 16384); // 16,384 B

    hipMemsetAsync(bits, 0, N_DIM * sizeof(unsigned), stream);

    prep1_kernel<<<M_DIM + 1024, 256, 0, stream>>>(lhs, rhs, sL, bits, ql);
    quant_rhs_t_kernel<<<dim3(N_DIM / 64, K_DIM / 64), 256, 0, stream>>>(
        rhs, bits, sR, qbT);
    gemm_i8_kernel<<<dim3((M_DIM / 256) * (N_DIM / 256)), 256, 0, stream>>>(
        ql, qbT, sL, sR, out);
}